// Round 5
// baseline (233.757 us; speedup 1.0000x reference)
//
#include <hip/hip_runtime.h>
#include <math.h>

typedef float vf4 __attribute__((ext_vector_type(4)));
typedef vf4 uvf4 __attribute__((aligned(4)));   // 16-B load at 4-B alignment
typedef float vf3 __attribute__((ext_vector_type(3)));
typedef vf3 uvf3 __attribute__((aligned(4)));

// ---------------------------------------------------------------------------
// Prep: rd[p] = sum of 3 channels of dmap pixel p (lane-contiguous reads,
// coalesced writes). Block 0 also computes per-batch scales:
//   sc[2n]   = cos(ang)*amp*(1/3)*(W/(W-1))
//   sc[2n+1] = sin(ang)*amp*(1/3)*(H/(H-1))
// ---------------------------------------------------------------------------
__global__ __launch_bounds__(256) void prep_kernel(
    const float* __restrict__ dmap, const float* __restrict__ amp,
    const float* __restrict__ ang, float* __restrict__ sc,
    float* __restrict__ rd, long long npix, int N, float fx, float fy) {
    long long p = (long long)blockIdx.x * 256 + threadIdx.x;
    if (p < npix) {
        const float* s = dmap + p * 3;
        rd[p] = s[0] + s[1] + s[2];
    }
    if (blockIdx.x == 0 && (int)threadIdx.x < N) {
        int i = threadIdx.x;
        float s_, c_;
        sincosf(ang[i], &s_, &c_);
        float a = amp[i] * (1.0f / 3.0f);
        sc[2 * i]     = c_ * a * fx;
        sc[2 * i + 1] = s_ * a * fy;
    }
}

// Branchless 12-B tap load via 16-B wide load; if p is the very last pixel of
// the whole image buffer, shift back one float and select (avoids OOB read).
__device__ __forceinline__ void tap_load(const float* p, const float* plast,
                                         float& r, float& g, float& b) {
    int off = (p == plast) ? 1 : 0;
    uvf4 v = *(const uvf4*)(p - off);
    r = off ? v.y : v.x;
    g = off ? v.z : v.y;
    b = off ? v.w : v.z;
}

// ---------------------------------------------------------------------------
// Main: H=W=1024, DH=DW=512, N=8. 256-thread blocks; each thread owns 4 rows
// at the same w (lane-contiguous gathers = fetch-minimal; 4 independent
// chains = latency hiding). dmap rows staged in LDS (moves interp loads off
// the vmem pipe). XCD k <-> image k swizzle for L2 locality.
// ---------------------------------------------------------------------------
__global__ __launch_bounds__(256) void displace_main(
    const float* __restrict__ img,   // 8,1024,1024,3
    const float* __restrict__ rd,    // 8,512,512 channel-summed dmap
    const float* __restrict__ sc,    // 16 scales
    float* __restrict__ out)         // 8,1024,1024,3
{
    const int lin  = (int)blockIdx.x;
    const int n    = lin & 7;           // XCD k <-> image k
    const int rest = lin >> 3;          // ascending per XCD
    const int h0   = (rest >> 2) << 2;  // row group of 4
    const int w0   = (rest & 3) << 8;
    const int w    = w0 + (int)threadIdx.x;

    const float* rbase = rd + (n << 18);
    const int base_x = (w0 >> 1) - 1;       // -1 when w0==0 (slot clamps)
    const int base_y = (h0 >> 1) - 1;

    // stage 4 dmap rows x 130 cols into LDS (slot (j,i) = clamped row/col)
    __shared__ float lds[4][132];
    for (int e = (int)threadIdx.x; e < 520; e += 256) {
        int j = e / 130;
        int i = e - j * 130;
        int row = min(max(base_y + j, 0), 511);
        int col = min(max(base_x + i, 0), 511);
        lds[j][i] = rbase[(row << 9) + col];
    }
    __syncthreads();

    const float scx = sc[2 * n];
    const float scy = sc[2 * n + 1];
    const float* ibase = img + (long long)n * (1024 * 1024 * 3);
    const float* plast = img + (8LL * 1024 * 1024 * 3 - 3);

    // x-side dmap interp (parity trick, exact for 2x half-pixel resize)
    const int sx0 = ((w - 1) >> 1) - base_x;
    const int sx1 = ((w + 1) >> 1) - base_x;
    const float tx = (w & 1) ? 0.25f : 0.75f;
    const float C = 1024.0f / 1023.0f;
    const float uxb = (float)w * C;

    #pragma unroll
    for (int k = 0; k < 4; ++k) {
        const int h = h0 + k;
        const int sy0 = ((h - 1) >> 1) - base_y;
        const int sy1 = ((h + 1) >> 1) - base_y;
        const float ty = (h & 1) ? 0.25f : 0.75f;

        float a0 = lds[sy0][sx0], b0 = lds[sy0][sx1];
        float a1 = lds[sy1][sx0], b1 = lds[sy1][sx1];
        float m0 = fmaf(b0 - a0, tx, a0);
        float m1 = fmaf(b1 - a1, tx, a1);
        float ds = fmaf(m1 - m0, ty, m0);

        // sample coords (+0.5 folded); |displacement| <= ~21 px
        float ux = fmaf(ds, scx, uxb);
        float uy = fmaf(ds, scy, (float)h * C);

        // reflect: single fold valid for u in (-2048, 2048)
        ux = fabsf(ux); if (ux >= 1024.0f) ux = 2048.0f - ux;
        uy = fabsf(uy); if (uy >= 1024.0f) uy = 2048.0f - uy;
        float ix = fminf(fmaxf(ux - 0.5f, 0.0f), 1023.0f);
        float iy = fminf(fmaxf(uy - 0.5f, 0.0f), 1023.0f);

        int ix0 = (int)ix;               // trunc == floor (ix >= 0)
        int iy0 = (int)iy;
        float wx = ix - (float)ix0;
        float wy = iy - (float)iy0;
        int ix1 = min(ix0 + 1, 1023);
        int iy1 = min(iy0 + 1, 1023);

        const float* Pa = ibase + ((iy0 << 10) + ix0) * 3;
        const float* Pb = ibase + ((iy0 << 10) + ix1) * 3;
        const float* Pc = ibase + ((iy1 << 10) + ix0) * 3;
        const float* Pd = ibase + ((iy1 << 10) + ix1) * 3;

        float ar, ag, ab, br, bg, bb, cr, cg, cb, dr, dg, db;
        tap_load(Pa, plast, ar, ag, ab);
        tap_load(Pb, plast, br, bg, bb);
        tap_load(Pc, plast, cr, cg, cb);
        tap_load(Pd, plast, dr, dg, db);

        const float wa = (1.0f - wx) * (1.0f - wy);
        const float wb = wx * (1.0f - wy);
        const float wc = (1.0f - wx) * wy;
        const float wd = wx * wy;

        uvf3 o;
        o.x = ar * wa + br * wb + cr * wc + dr * wd;
        o.y = ag * wa + bg * wb + cg * wc + dg * wd;
        o.z = ab * wa + bb * wb + cb * wc + db * wd;
        *(uvf3*)(out + (long long)(((n << 10 | h) << 10) + w) * 3) = o;
    }
}

// ---------------------------------------------------------------------------
// Generic fallback (R0 kernel, proven correct) for other shapes.
// ---------------------------------------------------------------------------
__device__ __forceinline__ float reflect_dyn(float x, float size) {
    x += 0.5f;
    float two = 2.0f * size;
    x = x - floorf(x / two) * two;
    if (x >= size) x = two - x;
    x -= 0.5f;
    return fminf(fmaxf(x, 0.0f), size - 1.0f);
}

__global__ __launch_bounds__(256) void displace_fallback(
    const float* __restrict__ img, const float* __restrict__ dmap,
    const float* __restrict__ amp, const float* __restrict__ ang,
    float* __restrict__ out, int N, int H, int W, int DH, int DW)
{
    long long idx = (long long)blockIdx.x * blockDim.x + threadIdx.x;
    long long total = (long long)N * H * W;
    if (idx >= total) return;
    int w = (int)(idx % W);
    long long t = idx / W;
    int h = (int)(t % H);
    int n = (int)(t / H);

    float sx = (w + 0.5f) * ((float)DW / (float)W) - 0.5f;
    float sy = (h + 0.5f) * ((float)DH / (float)H) - 0.5f;
    float fx = floorf(sx), fy = floorf(sy);
    float tx = sx - fx, ty = sy - fy;
    int dx0 = max(0, min(DW - 1, (int)fx));
    int dx1 = max(0, min(DW - 1, (int)fx + 1));
    int dy0 = max(0, min(DH - 1, (int)fy));
    int dy1 = max(0, min(DH - 1, (int)fy + 1));
    const float* dbase = dmap + (long long)n * DH * DW * 3;
    const float* p00 = dbase + ((long long)dy0 * DW + dx0) * 3;
    const float* p01 = dbase + ((long long)dy0 * DW + dx1) * 3;
    const float* p10 = dbase + ((long long)dy1 * DW + dx0) * 3;
    const float* p11 = dbase + ((long long)dy1 * DW + dx1) * 3;
    float m00 = p00[0] + p00[1] + p00[2];
    float m01 = p01[0] + p01[1] + p01[2];
    float m10 = p10[0] + p10[1] + p10[2];
    float m11 = p11[0] + p11[1] + p11[2];
    float dmv = ((m00 * (1.0f - tx) + m01 * tx) * (1.0f - ty)
               + (m10 * (1.0f - tx) + m11 * tx) * ty) * (1.0f / 3.0f);
    float a = amp[n], an = ang[n], sa, ca;
    sincosf(an, &sa, &ca);
    float d = dmv * a;
    float gx = -1.0f + 2.0f * (float)w / (float)(W - 1) + ca * d * (2.0f / (float)(W - 1));
    float gy = -1.0f + 2.0f * (float)h / (float)(H - 1) + sa * d * (2.0f / (float)(H - 1));
    float ixf2 = ((gx + 1.0f) * (float)W - 1.0f) * 0.5f;
    float iyf2 = ((gy + 1.0f) * (float)H - 1.0f) * 0.5f;
    ixf2 = reflect_dyn(ixf2, (float)W);
    iyf2 = reflect_dyn(iyf2, (float)H);
    float x0f = floorf(ixf2), y0f = floorf(iyf2);
    float wx = ixf2 - x0f, wy = iyf2 - y0f;
    int ix0 = min((int)x0f, W - 1);
    int ix1 = min((int)x0f + 1, W - 1);
    int iy0 = min((int)y0f, H - 1);
    int iy1 = min((int)y0f + 1, H - 1);
    const float* ibase = img + (long long)n * H * W * 3;
    const float* Ia = ibase + ((long long)iy0 * W + ix0) * 3;
    const float* Ib = ibase + ((long long)iy0 * W + ix1) * 3;
    const float* Ic = ibase + ((long long)iy1 * W + ix0) * 3;
    const float* Id = ibase + ((long long)iy1 * W + ix1) * 3;
    float wa = (1.0f - wx) * (1.0f - wy);
    float wb = wx * (1.0f - wy);
    float wc = (1.0f - wx) * wy;
    float wd = wx * wy;
    float* o = out + idx * 3;
    #pragma unroll
    for (int c = 0; c < 3; ++c)
        o[c] = Ia[c] * wa + Ib[c] * wb + Ic[c] * wc + Id[c] * wd;
}

extern "C" void kernel_launch(void* const* d_in, const int* in_sizes, int n_in,
                              void* d_out, int out_size, void* d_ws, size_t ws_size,
                              hipStream_t stream) {
    const float* img  = (const float*)d_in[0];
    const float* dmap = (const float*)d_in[1];
    const float* amp  = (const float*)d_in[2];
    const float* ang  = (const float*)d_in[3];
    float* out = (float*)d_out;

    int N = in_sizes[2];
    long long hw  = (long long)in_sizes[0] / ((long long)N * 3);
    int H = (int)llround(sqrt((double)hw));
    int W = H;
    long long dhw = (long long)in_sizes[1] / ((long long)N * 3);
    int DH = (int)llround(sqrt((double)dhw));
    int DW = DH;

    size_t need = 256 + (size_t)N * DH * DW * sizeof(float);

    if (H == 1024 && W == 1024 && DH == 512 && DW == 512 && N == 8 &&
        ws_size >= need) {
        float* sc = (float*)d_ws;
        float* rd = (float*)((char*)d_ws + 256);

        long long npix = (long long)N * DH * DW;
        int pgrid = (int)((npix + 255) / 256);
        prep_kernel<<<pgrid, 256, 0, stream>>>(
            dmap, amp, ang, sc, rd, npix, N,
            (float)W / (float)(W - 1), (float)H / (float)(H - 1));

        displace_main<<<8192, 256, 0, stream>>>(img, rd, sc, out);
    } else {
        long long total = (long long)N * H * W;
        int block = 256;
        long long grid = (total + block - 1) / block;
        displace_fallback<<<(dim3)(unsigned)grid, block, 0, stream>>>(
            img, dmap, amp, ang, out, N, H, W, DH, DW);
    }
}